// Round 17
// baseline (66.477 us; speedup 1.0000x reference)
//
#include <hip/hip_runtime.h>
#include <math.h>

#define NBANDS 5
#define BATCH  512
#define NPG    62
#define NTOT   (BATCH*NPG)     // 31744
#define F_IN   5
#define NH     8
#define NC     3
#define HC     (NH*NC)         // 24
#define EG     (NPG*16)        // 992 edges per graph
#define ETOT   (BATCH*EG)      // 507904
#define EPG    (EG+NPG)        // 1054 incl self loops
#define DE_DIM 930
#define KS     5
#define KLEN   186             // 930/5 = 31*6
#define XTS    9               // padded xt4 stride (144B, breaks 128B bank period)
#define CSTRIDE 80             // padded CSR stride
#define LOG2E  1.44269504088896340736f

// workspace layout (floats) — no zeroing required anywhere
#define WS_BN     0                        // 40 blocks * 10 partials (pad 512)
#define WS_LNS    512                      // 512 rows * {mu, rstd}
#define WS_POOLED 1536                     // 5*512*3 = 7680
#define WS_Q      (WS_POOLED + NBANDS*BATCH*NC)
#define WS_KT     (WS_Q  + BATCH*64)       // K transposed [64][512]
#define WS_V      (WS_KT + BATCH*64)
#define WS_PART   (WS_V  + BATCH*64)       // 3*KS*512*64
#define WS_END    (WS_PART + 3*KS*BATCH*64)

__device__ __forceinline__ float eluf(float x) { return x > 0.f ? x : expm1f(x); }

// ---------- kernel 1: BN chunk partials (blocks 0..39) + LN row stats ------
__global__ __launch_bounds__(256) void stats_kernel(
    const float* __restrict__ x, const float* __restrict__ de,
    float* __restrict__ ws) {
    int bid = blockIdx.x;
    int tid = threadIdx.x;
    int w = tid >> 6, lane = tid & 63;
    if (bid < 40) {                         // BN: band = bid/8, chunk = bid%8
        int band = bid >> 3, chunk = bid & 7;
        const int G4 = NTOT / 8 / 4;        // 992 groups of 4 rows
        const float4* xb4 =
            (const float4*)(x + (size_t)band * NTOT * F_IN) + (size_t)chunk * G4 * 5;
        float s[F_IN] = {0,0,0,0,0}, q[F_IN] = {0,0,0,0,0};
        for (int gi = tid; gi < G4; gi += 256) {
            const float4* p4 = xb4 + (size_t)gi * 5;
            float vv[20];
            *(float4*)&vv[0]  = p4[0];
            *(float4*)&vv[4]  = p4[1];
            *(float4*)&vv[8]  = p4[2];
            *(float4*)&vv[12] = p4[3];
            *(float4*)&vv[16] = p4[4];
            #pragma unroll
            for (int i = 0; i < 20; ++i) { float v = vv[i]; s[i % 5] += v; q[i % 5] += v * v; }
        }
        #pragma unroll
        for (int f = 0; f < F_IN; ++f) {
            for (int off = 32; off; off >>= 1) {
                s[f] += __shfl_down(s[f], off, 64);
                q[f] += __shfl_down(q[f], off, 64);
            }
        }
        __shared__ float part[4][10];
        if (lane == 0) {
            #pragma unroll
            for (int f = 0; f < F_IN; ++f) { part[w][f] = s[f]; part[w][5 + f] = q[f]; }
        }
        __syncthreads();
        if (tid < 10) {
            float t = part[0][tid] + part[1][tid] + part[2][tid] + part[3][tid];
            ws[WS_BN + (band * 8 + chunk) * 10 + tid] = t;
        }
    } else {                                // LN stats: 4 rows per block
        int r = (bid - 40) * 4 + w;
        const float* row = de + (size_t)r * DE_DIM;
        float s1 = 0.f, s2 = 0.f;
        for (int i = lane; i < DE_DIM; i += 64) { float v = row[i]; s1 += v; s2 += v * v; }
        #pragma unroll
        for (int off = 32; off; off >>= 1) {
            s1 += __shfl_down(s1, off, 64);
            s2 += __shfl_down(s2, off, 64);
        }
        if (lane == 0) {
            float mu  = s1 * (1.0f / DE_DIM);
            float var = s2 * (1.0f / DE_DIM) - mu * mu;
            ws[WS_LNS + r * 2]     = mu;
            ws[WS_LNS + r * 2 + 1] = rsqrtf(var + 1e-5f);
        }
    }
}

// ---------------- kernel 2: per-(band,graph) GAT + mean pool ---------------
// (r13 version — best measured) 3-barrier padded fixed-stride CSR.
__global__ __launch_bounds__(256) void gat_kernel(
    const float* __restrict__ x, const int* __restrict__ ei,
    const float* __restrict__ bn_g, const float* __restrict__ bn_b,
    const float* __restrict__ Wg, const float* __restrict__ attSg,
    const float* __restrict__ attDg, const float* __restrict__ biasg,
    const float* __restrict__ wsbn, float* __restrict__ pooled) {
    int g    = blockIdx.x;
    int band = blockIdx.y;
    __shared__ float4 xt4[NPG * XTS];          // 8928 B
    __shared__ float  Wl[F_IN * HC];
    __shared__ float  attS[HC], attD[HC];
    __shared__ float  bnsum[10];
    __shared__ float  scale[F_IN], shift[F_IN];
    __shared__ float  ald[NPG * NH];
    __shared__ int    deg[NPG];
    __shared__ unsigned short csr[NPG * CSTRIDE];  // slot 0 = self loop
    __shared__ float  outd[NPG][NC];

    int tid = threadIdx.x;
    int nbase = g * NPG;

    const int* srcp = ei + (size_t)band * 2 * ETOT + (size_t)g * EG;
    const int* dstp = srcp + ETOT;

    // P1: consts + bn partial reduce (+scale/shift, same wave) + deg init
    if (tid < F_IN * HC) Wl[tid] = Wg[band * F_IN * HC + tid];
    if (tid >= 128 && tid < 128 + HC) attS[tid - 128] = attSg[band * HC + tid - 128];
    if (tid >= 160 && tid < 160 + HC) attD[tid - 160] = attDg[band * HC + tid - 160];
    if (tid < NPG) deg[tid] = 0;
    if (tid >= 192 && tid < 202) {
        int f = tid - 192;
        float t = 0.f;
        #pragma unroll
        for (int c = 0; c < 8; ++c) t += wsbn[(band * 8 + c) * 10 + f];
        bnsum[f] = t;
    }
    if (tid >= 192 && tid < 192 + F_IN) {      // same wave as bnsum writers
        int f = tid - 192;
        float mu  = bnsum[f] * (1.0f / NTOT);
        float var = bnsum[5 + f] * (1.0f / NTOT) - mu * mu;
        float sc  = rsqrtf(var + 1e-5f) * bn_g[band * F_IN + f];
        scale[f] = sc;
        shift[f] = bn_b[band * F_IN + f] - mu * sc;
    }
    __syncthreads();

    // P2: direct padded-CSR scatter + self-loop slots + per-(n,h) features
    for (int e = tid; e < EG; e += 256) {
        int ls = srcp[e] - nbase;
        int ld = dstp[e] - nbase;
        int k = atomicAdd(&deg[ld], 1);
        if (k < CSTRIDE - 1) csr[ld * CSTRIDE + 1 + k] = (unsigned short)(ls * XTS);
    }
    if (tid < NPG) csr[tid * CSTRIDE] = (unsigned short)(tid * XTS);
    for (int p = tid; p < NPG * NH; p += 256) {
        int n = p >> 3, h = p & 7;
        const float* xr = x + (size_t)band * NTOT * F_IN + (size_t)(nbase + n) * F_IN;
        float c0 = 0.f, c1 = 0.f, c2 = 0.f;
        #pragma unroll
        for (int f = 0; f < F_IN; ++f) {
            float xv = xr[f] * scale[f] + shift[f];   // L1-cached, 8x reuse
            c0 += xv * Wl[f * HC + h * NC + 0];
            c1 += xv * Wl[f * HC + h * NC + 1];
            c2 += xv * Wl[f * HC + h * NC + 2];
        }
        float as = c0 * attS[h * NC] + c1 * attS[h * NC + 1] + c2 * attS[h * NC + 2];
        float ad = c0 * attD[h * NC] + c1 * attD[h * NC + 1] + c2 * attD[h * NC + 2];
        xt4[n * XTS + h] = make_float4(c0, c1, c2, as * LOG2E);
        ald[p] = ad * LOG2E;
    }
    __syncthreads();

    // P3: gather — (dst,head) per thread (2 items), one ds_read_b128 per edge
    for (int p = tid; p < NPG * NH; p += 256) {
        int d = p >> 3, h = p & 7;
        int s0 = d * CSTRIDE;
        int s1 = s0 + 1 + deg[d];
        float adv = ald[p];
        float den = 0.f, m0 = 0.f, m1 = 0.f, m2 = 0.f;
        #pragma unroll 2
        for (int e = s0; e < s1; ++e) {
            float4 t = xt4[csr[e] + h];
            float v = t.w + adv;
            v = fmaxf(v, 0.2f * v);              // leaky relu, branchless
            float ex = exp2f(v);                 // native v_exp_f32 (2^x)
            den += ex;
            m0 += ex * t.x;
            m1 += ex * t.y;
            m2 += ex * t.z;
        }
        float rd = 1.0f / den;
        float o0 = m0 * rd, o1 = m1 * rd, o2 = m2 * rd;
        #pragma unroll
        for (int off = 1; off < 8; off <<= 1) {   // head sum within 8-lane group
            o0 += __shfl_xor(o0, off, 64);
            o1 += __shfl_xor(o1, off, 64);
            o2 += __shfl_xor(o2, off, 64);
        }
        if (h == 0) { outd[d][0] = o0; outd[d][1] = o1; outd[d][2] = o2; }
    }
    __syncthreads();

    // P4: elu(head mean + bias) then graph mean pool
    float oc[NC] = {0.f, 0.f, 0.f};
    if (tid < NPG) {
        #pragma unroll
        for (int c = 0; c < NC; ++c)
            oc[c] = eluf(outd[tid][c] * (1.0f / NH) + biasg[band * NC + c]);
    }
    if (tid < 64) {
        #pragma unroll
        for (int c = 0; c < NC; ++c) {
            float v = oc[c];
            for (int off = 32; off; off >>= 1) v += __shfl_down(v, off, 64);
            if (tid == 0)
                pooled[((size_t)band * BATCH + g) * NC + c] = v * (1.0f / NPG);
        }
    }
}

// ---------- kernel 3: K-split QKV partials, 16 rows/block ------------------
// Each thread computes one col for rows w, w+4, w+8, w+12: every Wm load
// feeds FOUR FMAs (24 acc chains), quartering load-issue & Wm L2 traffic.
__global__ __launch_bounds__(256) void qkv_partial(
    const float* __restrict__ de, const float* __restrict__ lns,
    const float* __restrict__ ln_g, const float* __restrict__ ln_b,
    const float* __restrict__ qW, const float* __restrict__ kW,
    const float* __restrict__ vW, float* __restrict__ part) {
    int rt = blockIdx.x;                       // 0..31 (16 rows each)
    int m  = blockIdx.y;
    int ks = blockIdx.z;
    __shared__ float dl[16][KLEN];
    int tid = threadIdx.x, w = tid >> 6, col = tid & 63;
    for (int i = tid; i < 16 * KLEN; i += 256) {
        int rr = i / KLEN, ii = i - rr * KLEN;
        int row = rt * 16 + rr, gcol = ks * KLEN + ii;
        float mu = lns[row * 2], rstd = lns[row * 2 + 1];
        dl[rr][ii] = (de[(size_t)row * DE_DIM + gcol] - mu) * rstd * ln_g[gcol] + ln_b[gcol];
    }
    __syncthreads();
    const float* Wm = ((m == 0) ? qW : (m == 1) ? kW : vW) + (size_t)ks * KLEN * 64;
    float a0[6] = {0,0,0,0,0,0}, a1[6] = {0,0,0,0,0,0};
    float a2[6] = {0,0,0,0,0,0}, a3[6] = {0,0,0,0,0,0};
    for (int i = 0; i < KLEN; i += 6) {       // 186 = 31*6
        #pragma unroll
        for (int j = 0; j < 6; ++j) {
            float wv = Wm[(size_t)(i + j) * 64 + col];
            a0[j] += dl[w][i + j] * wv;
            a1[j] += dl[w + 4][i + j] * wv;
            a2[j] += dl[w + 8][i + j] * wv;
            a3[j] += dl[w + 12][i + j] * wv;
        }
    }
    float acc0 = ((a0[0] + a0[1]) + (a0[2] + a0[3])) + (a0[4] + a0[5]);
    float acc1 = ((a1[0] + a1[1]) + (a1[2] + a1[3])) + (a1[4] + a1[5]);
    float acc2 = ((a2[0] + a2[1]) + (a2[2] + a2[3])) + (a2[4] + a2[5]);
    float acc3 = ((a3[0] + a3[1]) + (a3[2] + a3[3])) + (a3[4] + a3[5]);
    size_t base = (((size_t)m * KS + ks) * BATCH + rt * 16) * 64 + col;
    part[base + (size_t)w * 64]        = acc0;
    part[base + (size_t)(w + 4) * 64]  = acc1;
    part[base + (size_t)(w + 8) * 64]  = acc2;
    part[base + (size_t)(w + 12) * 64] = acc3;
}

// ---------- kernel 4: reduce partials + bias; K is emitted transposed ------
__global__ __launch_bounds__(256) void qkv_reduce(
    const float* __restrict__ part,
    const float* __restrict__ qb, const float* __restrict__ kb,
    const float* __restrict__ vb,
    float* __restrict__ Q, float* __restrict__ KT, float* __restrict__ V) {
    int idx = blockIdx.x * 256 + threadIdx.x;   // 0 .. 3*512*64-1
    int m  = idx >> 15;                         // BATCH*64 = 32768
    int local = idx & 32767;
    if (m == 1) {                               // K -> KT[64][512], coalesced store
        int row = local & 511, col = local >> 9;
        float s = 0.f;
        #pragma unroll
        for (int ks = 0; ks < KS; ++ks)
            s += part[(((size_t)KS + ks) << 15) + (row << 6) + col];
        KT[local] = s + kb[col];                // local == col*512 + row
    } else {
        int col = local & 63;
        float s = 0.f;
        #pragma unroll
        for (int ks = 0; ks < KS; ++ks)
            s += part[(((size_t)m * KS + ks) << 15) + local];
        s += (m == 0) ? qb[col] : vb[col];
        ((m == 0) ? Q : V)[local] = s;
    }
}

// ---------------- fallback (ws too small): fused LN+QKV --------------------
__global__ __launch_bounds__(256) void qkv_fused_fb(
    const float* __restrict__ de, const float* __restrict__ ln_g,
    const float* __restrict__ ln_b,
    const float* __restrict__ qW, const float* __restrict__ qb,
    const float* __restrict__ kW, const float* __restrict__ kb,
    const float* __restrict__ vW, const float* __restrict__ vb,
    float* __restrict__ Q, float* __restrict__ KT, float* __restrict__ V) {
    int r0 = blockIdx.x * 4;
    int m  = blockIdx.y;
    __shared__ float dn[4][DE_DIM];
    int tid  = threadIdx.x;
    int w    = tid >> 6, lane = tid & 63;
    const float* row = de + (size_t)(r0 + w) * DE_DIM;
    float s1 = 0.f, s2 = 0.f;
    for (int i = lane; i < DE_DIM; i += 64) {
        float v = row[i]; dn[w][i] = v; s1 += v; s2 += v * v;
    }
    #pragma unroll
    for (int off = 32; off; off >>= 1) {
        s1 += __shfl_down(s1, off, 64);
        s2 += __shfl_down(s2, off, 64);
    }
    float mu   = __shfl(s1, 0, 64) * (1.0f / DE_DIM);
    float var  = __shfl(s2, 0, 64) * (1.0f / DE_DIM) - mu * mu;
    float rstd = rsqrtf(var + 1e-5f);
    for (int i = lane; i < DE_DIM; i += 64)
        dn[w][i] = (dn[w][i] - mu) * rstd * ln_g[i] + ln_b[i];
    __syncthreads();
    const float* Wm = (m == 0) ? qW : (m == 1) ? kW : vW;
    const float* bm = (m == 0) ? qb : (m == 1) ? kb : vb;
    float a[10];
    #pragma unroll
    for (int j = 0; j < 10; ++j) a[j] = 0.f;
    for (int i = 0; i < DE_DIM; i += 10) {
        #pragma unroll
        for (int j = 0; j < 10; ++j)
            a[j] += dn[w][i + j] * Wm[(size_t)(i + j) * 64 + lane];
    }
    float acc = (((a[0] + a[1]) + (a[2] + a[3])) + ((a[4] + a[5]) + (a[6] + a[7])))
              + (a[8] + a[9]) + bm[lane];
    int r = r0 + w;
    if (m == 1) KT[lane * BATCH + r] = acc;
    else ((m == 0) ? Q : V)[(size_t)r * 64 + lane] = acc;
}

// -------- kernel 5: attention + fusion tail, 2 queries per block -----------
// Each KT/V load feeds BOTH queries: K/V L2 traffic halves vs 1 query/block.
__global__ __launch_bounds__(256) void attn_final(
    const float* __restrict__ Q, const float* __restrict__ KT,
    const float* __restrict__ V, const float* __restrict__ pooled,
    const float* __restrict__ fgW, const float* __restrict__ fgb,
    const float* __restrict__ faW, const float* __restrict__ fab,
    float* __restrict__ out) {
    int b0 = blockIdx.x * 2;
    int tid = threadIdx.x;
    __shared__ float qrow[2][64];
    __shared__ float p[2][BATCH];
    __shared__ float red[2][8];
    __shared__ float pv[2][4][64];
    __shared__ float xde[2][64], xout[2][64];
    if (tid < 128)
        qrow[tid >> 6][tid & 63] = Q[(size_t)(b0 + (tid >> 6)) * 64 + (tid & 63)];
    __syncthreads();

    // scores: each KT element loaded once, used by both queries
    float s00 = 0.f, s01 = 0.f, s10 = 0.f, s11 = 0.f;   // s[q][jhalf]
    #pragma unroll 8
    for (int i = 0; i < 64; ++i) {
        float k0 = KT[(size_t)i * BATCH + tid];
        float k1 = KT[(size_t)i * BATCH + tid + 256];
        float q0 = qrow[0][i], q1 = qrow[1][i];
        s00 += q0 * k0; s01 += q0 * k1;
        s10 += q1 * k0; s11 += q1 * k1;
    }
    s00 *= 0.125f; s01 *= 0.125f; s10 *= 0.125f; s11 *= 0.125f;

    float mx0 = fmaxf(s00, s01), mx1 = fmaxf(s10, s11);
    for (int off = 32; off; off >>= 1) {
        mx0 = fmaxf(mx0, __shfl_down(mx0, off, 64));
        mx1 = fmaxf(mx1, __shfl_down(mx1, off, 64));
    }
    if ((tid & 63) == 0) { red[0][tid >> 6] = mx0; red[1][tid >> 6] = mx1; }
    __syncthreads();
    mx0 = fmaxf(fmaxf(red[0][0], red[0][1]), fmaxf(red[0][2], red[0][3]));
    mx1 = fmaxf(fmaxf(red[1][0], red[1][1]), fmaxf(red[1][2], red[1][3]));
    float e00 = __expf(s00 - mx0), e01 = __expf(s01 - mx0);
    float e10 = __expf(s10 - mx1), e11 = __expf(s11 - mx1);
    p[0][tid] = e00; p[0][tid + 256] = e01;
    p[1][tid] = e10; p[1][tid + 256] = e11;
    float sm0 = e00 + e01, sm1 = e10 + e11;
    for (int off = 32; off; off >>= 1) {
        sm0 += __shfl_down(sm0, off, 64);
        sm1 += __shfl_down(sm1, off, 64);
    }
    if ((tid & 63) == 0) { red[0][4 + (tid >> 6)] = sm0; red[1][4 + (tid >> 6)] = sm1; }
    __syncthreads();
    float den0 = red[0][4] + red[0][5] + red[0][6] + red[0][7];
    float den1 = red[1][4] + red[1][5] + red[1][6] + red[1][7];

    // P @ V: each V element loaded once, 2 FMAs
    int o = tid & 63, cq = tid >> 6;
    float acc0 = 0.f, acc1 = 0.f;
    #pragma unroll 4
    for (int j = cq * 128; j < cq * 128 + 128; ++j) {
        float vv = V[(size_t)j * 64 + o];
        acc0 += p[0][j] * vv;
        acc1 += p[1][j] * vv;
    }
    pv[0][cq][o] = acc0;
    pv[1][cq][o] = acc1;
    __syncthreads();
    if (tid < 128) {
        int qi = tid >> 6, oo = tid & 63;
        float dn = qi ? den1 : den0;
        xde[qi][oo] = (pv[qi][0][oo] + pv[qi][1][oo] + pv[qi][2][oo] + pv[qi][3][oo]) / dn;
    } else {
        int qi = (tid - 128) >> 6, oo = tid & 63;
        int b = b0 + qi;
        float a = fgb[oo];
        #pragma unroll
        for (int j = 0; j < NBANDS * NC; ++j) {
            int band = j / NC, c = j % NC;
            a += pooled[((size_t)band * BATCH + b) * NC + c] * fgW[j * 64 + oo];
        }
        xout[qi][oo] = eluf(a);
    }
    __syncthreads();
    if (tid < 2 * NC) {
        int qi = tid / NC, c = tid - qi * NC;
        float a = fab[c];
        for (int i = 0; i < 64; ++i) a += xout[qi][i] * faW[i * NC + c];
        for (int i = 0; i < 64; ++i) a += xde[qi][i] * faW[(64 + i) * NC + c];
        out[(size_t)(b0 + qi) * NC + c] = eluf(a);
    }
}

extern "C" void kernel_launch(void* const* d_in, const int* in_sizes, int n_in,
                              void* d_out, int out_size, void* d_ws, size_t ws_size,
                              hipStream_t stream) {
    const float* x     = (const float*)d_in[0];
    const int*   ei    = (const int*)  d_in[1];
    const float* de    = (const float*)d_in[3];
    const float* bn_g  = (const float*)d_in[4];
    const float* bn_b  = (const float*)d_in[5];
    const float* W     = (const float*)d_in[6];
    const float* attS  = (const float*)d_in[7];
    const float* attD  = (const float*)d_in[8];
    const float* gbias = (const float*)d_in[9];
    const float* fgW   = (const float*)d_in[10];
    const float* fgb   = (const float*)d_in[11];
    const float* ln_g  = (const float*)d_in[12];
    const float* ln_b  = (const float*)d_in[13];
    const float* qW    = (const float*)d_in[14];
    const float* qb    = (const float*)d_in[15];
    const float* kW    = (const float*)d_in[16];
    const float* kb    = (const float*)d_in[17];
    const float* vW    = (const float*)d_in[18];
    const float* vb    = (const float*)d_in[19];
    const float* faW   = (const float*)d_in[20];
    const float* fab   = (const float*)d_in[21];
    float* ws  = (float*)d_ws;
    float* out = (float*)d_out;

    stats_kernel<<<168, 256, 0, stream>>>(x, de, ws);
    gat_kernel<<<dim3(BATCH, NBANDS), 256, 0, stream>>>(
        x, ei, bn_g, bn_b, W, attS, attD, gbias, ws + WS_BN, ws + WS_POOLED);

    if (ws_size >= (size_t)WS_END * sizeof(float)) {
        qkv_partial<<<dim3(BATCH / 16, 3, KS), 256, 0, stream>>>(
            de, ws + WS_LNS, ln_g, ln_b, qW, kW, vW, ws + WS_PART);
        qkv_reduce<<<(3 * BATCH * 64) / 256, 256, 0, stream>>>(
            ws + WS_PART, qb, kb, vb, ws + WS_Q, ws + WS_KT, ws + WS_V);
    } else {
        qkv_fused_fb<<<dim3(BATCH / 4, 3), 256, 0, stream>>>(
            de, ln_g, ln_b, qW, qb, kW, kb, vW, vb,
            ws + WS_Q, ws + WS_KT, ws + WS_V);
    }
    attn_final<<<BATCH / 2, 256, 0, stream>>>(ws + WS_Q, ws + WS_KT, ws + WS_V,
                                              ws + WS_POOLED, fgW, fgb, faW, fab, out);
}

// Round 18
// 63.065 us; speedup vs baseline: 1.0541x; 1.0541x over previous
//
#include <hip/hip_runtime.h>
#include <math.h>

#define NBANDS 5
#define BATCH  512
#define NPG    62
#define NTOT   (BATCH*NPG)     // 31744
#define F_IN   5
#define NH     8
#define NC     3
#define HC     (NH*NC)         // 24
#define EG     (NPG*16)        // 992 edges per graph
#define ETOT   (BATCH*EG)      // 507904
#define EPG    (EG+NPG)        // 1054 incl self loops
#define DE_DIM 930
#define KS     5
#define KLEN   186             // 930/5 = 31*6
#define XTS    9               // padded xt4 stride (144B, breaks 128B bank period)
#define CSTRIDE 80             // padded CSR stride
#define LOG2E  1.44269504088896340736f

// workspace layout (floats) — no zeroing required anywhere
#define WS_BN     0                        // 40 blocks * 10 partials (pad 512)
#define WS_LNS    512                      // 512 rows * {mu, rstd}
#define WS_POOLED 1536                     // 5*512*3 = 7680
#define WS_Q      (WS_POOLED + NBANDS*BATCH*NC)
#define WS_KT     (WS_Q  + BATCH*64)       // K transposed [64][512]
#define WS_V      (WS_KT + BATCH*64)
#define WS_PART   (WS_V  + BATCH*64)       // 3*KS*512*64
#define WS_END    (WS_PART + 3*KS*BATCH*64)

__device__ __forceinline__ float eluf(float x) { return x > 0.f ? x : expm1f(x); }

// ---------- kernel 1: BN chunk partials (blocks 0..39) + LN row stats ------
__global__ __launch_bounds__(256) void stats_kernel(
    const float* __restrict__ x, const float* __restrict__ de,
    float* __restrict__ ws) {
    int bid = blockIdx.x;
    int tid = threadIdx.x;
    int w = tid >> 6, lane = tid & 63;
    if (bid < 40) {                         // BN: band = bid/8, chunk = bid%8
        int band = bid >> 3, chunk = bid & 7;
        const int G4 = NTOT / 8 / 4;        // 992 groups of 4 rows
        const float4* xb4 =
            (const float4*)(x + (size_t)band * NTOT * F_IN) + (size_t)chunk * G4 * 5;
        float s[F_IN] = {0,0,0,0,0}, q[F_IN] = {0,0,0,0,0};
        for (int gi = tid; gi < G4; gi += 256) {
            const float4* p4 = xb4 + (size_t)gi * 5;
            float vv[20];
            *(float4*)&vv[0]  = p4[0];
            *(float4*)&vv[4]  = p4[1];
            *(float4*)&vv[8]  = p4[2];
            *(float4*)&vv[12] = p4[3];
            *(float4*)&vv[16] = p4[4];
            #pragma unroll
            for (int i = 0; i < 20; ++i) { float v = vv[i]; s[i % 5] += v; q[i % 5] += v * v; }
        }
        #pragma unroll
        for (int f = 0; f < F_IN; ++f) {
            for (int off = 32; off; off >>= 1) {
                s[f] += __shfl_down(s[f], off, 64);
                q[f] += __shfl_down(q[f], off, 64);
            }
        }
        __shared__ float part[4][10];
        if (lane == 0) {
            #pragma unroll
            for (int f = 0; f < F_IN; ++f) { part[w][f] = s[f]; part[w][5 + f] = q[f]; }
        }
        __syncthreads();
        if (tid < 10) {
            float t = part[0][tid] + part[1][tid] + part[2][tid] + part[3][tid];
            ws[WS_BN + (band * 8 + chunk) * 10 + tid] = t;
        }
    } else {                                // LN stats: 4 rows per block
        int r = (bid - 40) * 4 + w;
        const float* row = de + (size_t)r * DE_DIM;
        float s1 = 0.f, s2 = 0.f;
        for (int i = lane; i < DE_DIM; i += 64) { float v = row[i]; s1 += v; s2 += v * v; }
        #pragma unroll
        for (int off = 32; off; off >>= 1) {
            s1 += __shfl_down(s1, off, 64);
            s2 += __shfl_down(s2, off, 64);
        }
        if (lane == 0) {
            float mu  = s1 * (1.0f / DE_DIM);
            float var = s2 * (1.0f / DE_DIM) - mu * mu;
            ws[WS_LNS + r * 2]     = mu;
            ws[WS_LNS + r * 2 + 1] = rsqrtf(var + 1e-5f);
        }
    }
}

// ---------------- kernel 2: per-(band,graph) GAT + mean pool ---------------
// (r13 version — best measured) 3-barrier padded fixed-stride CSR.
__global__ __launch_bounds__(256) void gat_kernel(
    const float* __restrict__ x, const int* __restrict__ ei,
    const float* __restrict__ bn_g, const float* __restrict__ bn_b,
    const float* __restrict__ Wg, const float* __restrict__ attSg,
    const float* __restrict__ attDg, const float* __restrict__ biasg,
    const float* __restrict__ wsbn, float* __restrict__ pooled) {
    int g    = blockIdx.x;
    int band = blockIdx.y;
    __shared__ float4 xt4[NPG * XTS];          // 8928 B
    __shared__ float  Wl[F_IN * HC];
    __shared__ float  attS[HC], attD[HC];
    __shared__ float  bnsum[10];
    __shared__ float  scale[F_IN], shift[F_IN];
    __shared__ float  ald[NPG * NH];
    __shared__ int    deg[NPG];
    __shared__ unsigned short csr[NPG * CSTRIDE];  // slot 0 = self loop
    __shared__ float  outd[NPG][NC];

    int tid = threadIdx.x;
    int nbase = g * NPG;

    const int* srcp = ei + (size_t)band * 2 * ETOT + (size_t)g * EG;
    const int* dstp = srcp + ETOT;

    // P1: consts + bn partial reduce (+scale/shift, same wave) + deg init
    if (tid < F_IN * HC) Wl[tid] = Wg[band * F_IN * HC + tid];
    if (tid >= 128 && tid < 128 + HC) attS[tid - 128] = attSg[band * HC + tid - 128];
    if (tid >= 160 && tid < 160 + HC) attD[tid - 160] = attDg[band * HC + tid - 160];
    if (tid < NPG) deg[tid] = 0;
    if (tid >= 192 && tid < 202) {
        int f = tid - 192;
        float t = 0.f;
        #pragma unroll
        for (int c = 0; c < 8; ++c) t += wsbn[(band * 8 + c) * 10 + f];
        bnsum[f] = t;
    }
    if (tid >= 192 && tid < 192 + F_IN) {      // same wave as bnsum writers
        int f = tid - 192;
        float mu  = bnsum[f] * (1.0f / NTOT);
        float var = bnsum[5 + f] * (1.0f / NTOT) - mu * mu;
        float sc  = rsqrtf(var + 1e-5f) * bn_g[band * F_IN + f];
        scale[f] = sc;
        shift[f] = bn_b[band * F_IN + f] - mu * sc;
    }
    __syncthreads();

    // P2: direct padded-CSR scatter + self-loop slots + per-(n,h) features
    for (int e = tid; e < EG; e += 256) {
        int ls = srcp[e] - nbase;
        int ld = dstp[e] - nbase;
        int k = atomicAdd(&deg[ld], 1);
        if (k < CSTRIDE - 1) csr[ld * CSTRIDE + 1 + k] = (unsigned short)(ls * XTS);
    }
    if (tid < NPG) csr[tid * CSTRIDE] = (unsigned short)(tid * XTS);
    for (int p = tid; p < NPG * NH; p += 256) {
        int n = p >> 3, h = p & 7;
        const float* xr = x + (size_t)band * NTOT * F_IN + (size_t)(nbase + n) * F_IN;
        float c0 = 0.f, c1 = 0.f, c2 = 0.f;
        #pragma unroll
        for (int f = 0; f < F_IN; ++f) {
            float xv = xr[f] * scale[f] + shift[f];   // L1-cached, 8x reuse
            c0 += xv * Wl[f * HC + h * NC + 0];
            c1 += xv * Wl[f * HC + h * NC + 1];
            c2 += xv * Wl[f * HC + h * NC + 2];
        }
        float as = c0 * attS[h * NC] + c1 * attS[h * NC + 1] + c2 * attS[h * NC + 2];
        float ad = c0 * attD[h * NC] + c1 * attD[h * NC + 1] + c2 * attD[h * NC + 2];
        xt4[n * XTS + h] = make_float4(c0, c1, c2, as * LOG2E);
        ald[p] = ad * LOG2E;
    }
    __syncthreads();

    // P3: gather — (dst,head) per thread (2 items), one ds_read_b128 per edge
    for (int p = tid; p < NPG * NH; p += 256) {
        int d = p >> 3, h = p & 7;
        int s0 = d * CSTRIDE;
        int s1 = s0 + 1 + deg[d];
        float adv = ald[p];
        float den = 0.f, m0 = 0.f, m1 = 0.f, m2 = 0.f;
        #pragma unroll 2
        for (int e = s0; e < s1; ++e) {
            float4 t = xt4[csr[e] + h];
            float v = t.w + adv;
            v = fmaxf(v, 0.2f * v);              // leaky relu, branchless
            float ex = exp2f(v);                 // native v_exp_f32 (2^x)
            den += ex;
            m0 += ex * t.x;
            m1 += ex * t.y;
            m2 += ex * t.z;
        }
        float rd = 1.0f / den;
        float o0 = m0 * rd, o1 = m1 * rd, o2 = m2 * rd;
        #pragma unroll
        for (int off = 1; off < 8; off <<= 1) {   // head sum within 8-lane group
            o0 += __shfl_xor(o0, off, 64);
            o1 += __shfl_xor(o1, off, 64);
            o2 += __shfl_xor(o2, off, 64);
        }
        if (h == 0) { outd[d][0] = o0; outd[d][1] = o1; outd[d][2] = o2; }
    }
    __syncthreads();

    // P4: elu(head mean + bias) then graph mean pool
    float oc[NC] = {0.f, 0.f, 0.f};
    if (tid < NPG) {
        #pragma unroll
        for (int c = 0; c < NC; ++c)
            oc[c] = eluf(outd[tid][c] * (1.0f / NH) + biasg[band * NC + c]);
    }
    if (tid < 64) {
        #pragma unroll
        for (int c = 0; c < NC; ++c) {
            float v = oc[c];
            for (int off = 32; off; off >>= 1) v += __shfl_down(v, off, 64);
            if (tid == 0)
                pooled[((size_t)band * BATCH + g) * NC + c] = v * (1.0f / NPG);
        }
    }
}

// ---------- kernel 3: K-split QKV partials, 8 rows/block -------------------
// Each thread computes one col for rows w and w+4: every Wm load feeds TWO
// FMAs (12 acc chains), halving load-issue pressure and Wm L2 traffic.
__global__ __launch_bounds__(256) void qkv_partial(
    const float* __restrict__ de, const float* __restrict__ lns,
    const float* __restrict__ ln_g, const float* __restrict__ ln_b,
    const float* __restrict__ qW, const float* __restrict__ kW,
    const float* __restrict__ vW, float* __restrict__ part) {
    int rt = blockIdx.x;                       // 0..63 (8 rows each)
    int m  = blockIdx.y;
    int ks = blockIdx.z;
    __shared__ float dl[8][KLEN];
    int tid = threadIdx.x, w = tid >> 6, col = tid & 63;
    for (int i = tid; i < 8 * KLEN; i += 256) {
        int rr = i / KLEN, ii = i - rr * KLEN;
        int row = rt * 8 + rr, gcol = ks * KLEN + ii;
        float mu = lns[row * 2], rstd = lns[row * 2 + 1];
        dl[rr][ii] = (de[(size_t)row * DE_DIM + gcol] - mu) * rstd * ln_g[gcol] + ln_b[gcol];
    }
    __syncthreads();
    const float* Wm = ((m == 0) ? qW : (m == 1) ? kW : vW) + (size_t)ks * KLEN * 64;
    float a0[6] = {0, 0, 0, 0, 0, 0};
    float a1[6] = {0, 0, 0, 0, 0, 0};
    for (int i = 0; i < KLEN; i += 6) {       // 186 = 31*6
        #pragma unroll
        for (int j = 0; j < 6; ++j) {
            float wv = Wm[(size_t)(i + j) * 64 + col];
            a0[j] += dl[w][i + j] * wv;
            a1[j] += dl[w + 4][i + j] * wv;
        }
    }
    float acc0 = ((a0[0] + a0[1]) + (a0[2] + a0[3])) + (a0[4] + a0[5]);
    float acc1 = ((a1[0] + a1[1]) + (a1[2] + a1[3])) + (a1[4] + a1[5]);
    size_t base = (((size_t)m * KS + ks) * BATCH + rt * 8) * 64 + col;
    part[base + (size_t)w * 64]       = acc0;
    part[base + (size_t)(w + 4) * 64] = acc1;
}

// ---------- kernel 4: reduce partials + bias; K is emitted transposed ------
__global__ __launch_bounds__(256) void qkv_reduce(
    const float* __restrict__ part,
    const float* __restrict__ qb, const float* __restrict__ kb,
    const float* __restrict__ vb,
    float* __restrict__ Q, float* __restrict__ KT, float* __restrict__ V) {
    int idx = blockIdx.x * 256 + threadIdx.x;   // 0 .. 3*512*64-1
    int m  = idx >> 15;                         // BATCH*64 = 32768
    int local = idx & 32767;
    if (m == 1) {                               // K -> KT[64][512], coalesced store
        int row = local & 511, col = local >> 9;
        float s = 0.f;
        #pragma unroll
        for (int ks = 0; ks < KS; ++ks)
            s += part[(((size_t)KS + ks) << 15) + (row << 6) + col];
        KT[local] = s + kb[col];                // local == col*512 + row
    } else {
        int col = local & 63;
        float s = 0.f;
        #pragma unroll
        for (int ks = 0; ks < KS; ++ks)
            s += part[(((size_t)m * KS + ks) << 15) + local];
        s += (m == 0) ? qb[col] : vb[col];
        ((m == 0) ? Q : V)[local] = s;
    }
}

// ---------------- fallback (ws too small): fused LN+QKV --------------------
__global__ __launch_bounds__(256) void qkv_fused_fb(
    const float* __restrict__ de, const float* __restrict__ ln_g,
    const float* __restrict__ ln_b,
    const float* __restrict__ qW, const float* __restrict__ qb,
    const float* __restrict__ kW, const float* __restrict__ kb,
    const float* __restrict__ vW, const float* __restrict__ vb,
    float* __restrict__ Q, float* __restrict__ KT, float* __restrict__ V) {
    int r0 = blockIdx.x * 4;
    int m  = blockIdx.y;
    __shared__ float dn[4][DE_DIM];
    int tid  = threadIdx.x;
    int w    = tid >> 6, lane = tid & 63;
    const float* row = de + (size_t)(r0 + w) * DE_DIM;
    float s1 = 0.f, s2 = 0.f;
    for (int i = lane; i < DE_DIM; i += 64) {
        float v = row[i]; dn[w][i] = v; s1 += v; s2 += v * v;
    }
    #pragma unroll
    for (int off = 32; off; off >>= 1) {
        s1 += __shfl_down(s1, off, 64);
        s2 += __shfl_down(s2, off, 64);
    }
    float mu   = __shfl(s1, 0, 64) * (1.0f / DE_DIM);
    float var  = __shfl(s2, 0, 64) * (1.0f / DE_DIM) - mu * mu;
    float rstd = rsqrtf(var + 1e-5f);
    for (int i = lane; i < DE_DIM; i += 64)
        dn[w][i] = (dn[w][i] - mu) * rstd * ln_g[i] + ln_b[i];
    __syncthreads();
    const float* Wm = (m == 0) ? qW : (m == 1) ? kW : vW;
    const float* bm = (m == 0) ? qb : (m == 1) ? kb : vb;
    float a[10];
    #pragma unroll
    for (int j = 0; j < 10; ++j) a[j] = 0.f;
    for (int i = 0; i < DE_DIM; i += 10) {
        #pragma unroll
        for (int j = 0; j < 10; ++j)
            a[j] += dn[w][i + j] * Wm[(size_t)(i + j) * 64 + lane];
    }
    float acc = (((a[0] + a[1]) + (a[2] + a[3])) + ((a[4] + a[5]) + (a[6] + a[7])))
              + (a[8] + a[9]) + bm[lane];
    int r = r0 + w;
    if (m == 1) KT[lane * BATCH + r] = acc;
    else ((m == 0) ? Q : V)[(size_t)r * 64 + lane] = acc;
}

// ---------------- kernel 5: attention + fusion tail ------------------------
__global__ __launch_bounds__(256) void attn_final(
    const float* __restrict__ Q, const float* __restrict__ KT,
    const float* __restrict__ V, const float* __restrict__ pooled,
    const float* __restrict__ fgW, const float* __restrict__ fgb,
    const float* __restrict__ faW, const float* __restrict__ fab,
    float* __restrict__ out) {
    int b = blockIdx.x;
    int tid = threadIdx.x;
    __shared__ float qrow[64];
    __shared__ float p[BATCH];
    __shared__ float red[8];
    __shared__ float pv[4][64];
    __shared__ float xde[64], xout[64];
    if (tid < 64) qrow[tid] = Q[(size_t)b * 64 + tid];
    __syncthreads();

    // scores: fully-coalesced KT reads (lane j reads KT[i][j])
    float a0 = 0.f, a1 = 0.f, b0 = 0.f, b1 = 0.f;
    #pragma unroll 8
    for (int i = 0; i < 64; i += 2) {
        float q0 = qrow[i], q1 = qrow[i + 1];
        a0 += q0 * KT[(size_t)i * BATCH + tid];
        a1 += q1 * KT[(size_t)(i + 1) * BATCH + tid];
        b0 += q0 * KT[(size_t)i * BATCH + tid + 256];
        b1 += q1 * KT[(size_t)(i + 1) * BATCH + tid + 256];
    }
    float sj0 = (a0 + a1) * 0.125f, sj1 = (b0 + b1) * 0.125f;

    float mx = fmaxf(sj0, sj1);
    for (int off = 32; off; off >>= 1) mx = fmaxf(mx, __shfl_down(mx, off, 64));
    if ((tid & 63) == 0) red[tid >> 6] = mx;
    __syncthreads();
    mx = fmaxf(fmaxf(red[0], red[1]), fmaxf(red[2], red[3]));
    float e0 = __expf(sj0 - mx), e1 = __expf(sj1 - mx);
    p[tid] = e0; p[tid + 256] = e1;
    float s = e0 + e1;
    for (int off = 32; off; off >>= 1) s += __shfl_down(s, off, 64);
    if ((tid & 63) == 0) red[4 + (tid >> 6)] = s;
    __syncthreads();
    float denom = red[4] + red[5] + red[6] + red[7];

    int o = tid & 63, cq = tid >> 6;
    float acc = 0.f;
    #pragma unroll 4
    for (int j = cq * 128; j < cq * 128 + 128; ++j)
        acc += p[j] * V[(size_t)j * 64 + o];
    pv[cq][o] = acc;
    __syncthreads();
    if (tid < 64)
        xde[tid] = (pv[0][tid] + pv[1][tid] + pv[2][tid] + pv[3][tid]) / denom;
    if (tid >= 64 && tid < 128) {
        int oo = tid - 64;
        float a = fgb[oo];
        #pragma unroll
        for (int j = 0; j < NBANDS * NC; ++j) {
            int band = j / NC, c = j % NC;
            a += pooled[((size_t)band * BATCH + b) * NC + c] * fgW[j * 64 + oo];
        }
        xout[oo] = eluf(a);
    }
    __syncthreads();
    if (tid < NC) {
        float a = fab[tid];
        for (int i = 0; i < 64; ++i) a += xout[i] * faW[i * NC + tid];
        for (int i = 0; i < 64; ++i) a += xde[i] * faW[(64 + i) * NC + tid];
        out[(size_t)b * NC + tid] = eluf(a);
    }
}

extern "C" void kernel_launch(void* const* d_in, const int* in_sizes, int n_in,
                              void* d_out, int out_size, void* d_ws, size_t ws_size,
                              hipStream_t stream) {
    const float* x     = (const float*)d_in[0];
    const int*   ei    = (const int*)  d_in[1];
    const float* de    = (const float*)d_in[3];
    const float* bn_g  = (const float*)d_in[4];
    const float* bn_b  = (const float*)d_in[5];
    const float* W     = (const float*)d_in[6];
    const float* attS  = (const float*)d_in[7];
    const float* attD  = (const float*)d_in[8];
    const float* gbias = (const float*)d_in[9];
    const float* fgW   = (const float*)d_in[10];
    const float* fgb   = (const float*)d_in[11];
    const float* ln_g  = (const float*)d_in[12];
    const float* ln_b  = (const float*)d_in[13];
    const float* qW    = (const float*)d_in[14];
    const float* qb    = (const float*)d_in[15];
    const float* kW    = (const float*)d_in[16];
    const float* kb    = (const float*)d_in[17];
    const float* vW    = (const float*)d_in[18];
    const float* vb    = (const float*)d_in[19];
    const float* faW   = (const float*)d_in[20];
    const float* fab   = (const float*)d_in[21];
    float* ws  = (float*)d_ws;
    float* out = (float*)d_out;

    stats_kernel<<<168, 256, 0, stream>>>(x, de, ws);
    gat_kernel<<<dim3(BATCH, NBANDS), 256, 0, stream>>>(
        x, ei, bn_g, bn_b, W, attS, attD, gbias, ws + WS_BN, ws + WS_POOLED);

    if (ws_size >= (size_t)WS_END * sizeof(float)) {
        qkv_partial<<<dim3(BATCH / 8, 3, KS), 256, 0, stream>>>(
            de, ws + WS_LNS, ln_g, ln_b, qW, kW, vW, ws + WS_PART);
        qkv_reduce<<<(3 * BATCH * 64) / 256, 256, 0, stream>>>(
            ws + WS_PART, qb, kb, vb, ws + WS_Q, ws + WS_KT, ws + WS_V);
    } else {
        qkv_fused_fb<<<dim3(BATCH / 4, 3), 256, 0, stream>>>(
            de, ln_g, ln_b, qW, qb, kW, kb, vW, vb,
            ws + WS_Q, ws + WS_KT, ws + WS_V);
    }
    attn_final<<<BATCH, 256, 0, stream>>>(ws + WS_Q, ws + WS_KT, ws + WS_V,
                                          ws + WS_POOLED, fgW, fgb, faW, fab, out);
}